// Round 8
// baseline (227.434 us; speedup 1.0000x reference)
//
#include <hip/hip_runtime.h>

// ============================================================================
// ContDecoder on MI355X — bf16 MFMA, round 10: 32x32x16 MFMA conversion.
// MPTS=32, 1024 threads (16 waves), 55.8 KB dynamic LDS, 2 blocks/CU.
//
// r9 post-mortem refuted LDS-throughput-bound (k-split cut traffic, time
// rose); kernel is latency-bound with no saturated pipe. r10 halves ALL
// per-op counts structurally via the MFMA shape: 32x32x16 does the same
// 8192 MACs as 16x16x32 with a 32-wide n-tile -> per block: ds_read
// 972->492, MFMA 972->492, addressing VALU ~halved, conflicts ~halved.
// No new barriers, no k-split, no wave-mapping machinery.
//   - C/D map (m74/m101 HW-verified): col=lane&31, row=(reg&3)+8*(reg>>2)
//     +4*(lane>>5). Swapped operands mfma(W,X): row=n, col=pt.
//   - A/B map (K-doubling rule, same as our verified 16x16x32 pack):
//     row/col = lane&31, k = (lane>>5)*8 + j.
//   - Epilogue: 4 quads of 4 consecutive n per lane -> 4x ds_write_b64.
// Kept: row layout [xin 0..64 | hA 64..608 | hB 608..864] stride 872,
// f2bf RNE, float4 bias, zero-packed pad weights, pad-neuron bias 0.
// ============================================================================

#define NTH     1024
#define NWAVES  16
#define MPTS    32              // points per block = one 32-wide M-tile
#define SROW    872             // LDS row stride in bf16 elems (1744 B)
#define XIN_OFF 0
#define HA_OFF  64
#define HB_OFF  608
#define NPOINTS (8 * 16384)
#define GRIDX   (NPOINTS / MPTS)   // 4096 blocks
#define LDSBYTES (MPTS * SROW * 2) // 55808 -> 2 blocks/CU

typedef short          short8  __attribute__((ext_vector_type(8)));
typedef short          short4v __attribute__((ext_vector_type(4)));
typedef float          f32x4   __attribute__((ext_vector_type(4)));
typedef float          f32x16  __attribute__((ext_vector_type(16)));
typedef unsigned short u16;

__device__ __forceinline__ u16 f2bf(float f) {
    unsigned int u = __builtin_bit_cast(unsigned int, f);
    u += 0x7fffu + ((u >> 16) & 1u);        // round-to-nearest-even
    return (u16)(u >> 16);
}

// ---------------------------------------------------------------------------
// Packed-weight geometry for 32x32x16: 16B fragments of 8 bf16.
// frag64 (l, nt, s), lane: holds W[s*16 + (lane>>5)*8 + j][nt*32 + (lane&31)],
// j=0..7, zero-padded outside (kact, nact).
//   l : KHpad KSteps(16) Ntiles(32) frag64_base
//   0 :    0     4          17          0
//   1 :  544    38           8         68
//   2 :  256    20           4        372
//   3 :  128    12           2        452
//   4 :   64     8           1        476
//   5 :   32     6           1        484
//   6 :   32     2           1        490   total 492 frag64 = 503808 B
// ---------------------------------------------------------------------------
__constant__ int pk_base[8] = {0, 68, 372, 452, 476, 484, 490, 492};
__constant__ int pk_ks[7]   = {4, 38, 20, 12, 8, 6, 2};
__constant__ int pk_khp[7]  = {0, 544, 256, 128, 64, 32, 32};
__constant__ int pk_kact[7] = {0, 516, 256, 128, 64, 32, 16};
__constant__ int pk_nact[7] = {516, 256, 128, 64, 32, 16, 2};

struct WPtrs { const float* W[7]; };

// One thread = one 16B fragment slice (frag64 = t>>6, lane = t&63).
// Reads coalesce across lanes (32 consecutive n); writes perfectly coalesced.
__global__ void pack_weights(WPtrs wp, u16* __restrict__ out)
{
    const int t = blockIdx.x * blockDim.x + threadIdx.x;
    if (t >= 492 * 64) return;
    const int frag = t >> 6;
    const int lane = t & 63;
    int l = 0;
    while (l < 6 && frag >= pk_base[l + 1]) ++l;
    const int r    = frag - pk_base[l];
    const int ks   = pk_ks[l];
    const int s    = r % ks;
    const int nt   = r / ks;
    const int n    = nt * 32 + (lane & 31);
    const int k0   = s * 16 + (lane >> 5) * 8;
    const int nact = pk_nact[l];
    const int khp  = pk_khp[l];
    const int kact = pk_kact[l];
    const float* W = wp.W[l];

    union { short8 v; u16 e[8]; } fr;
#pragma unroll
    for (int j = 0; j < 8; ++j) {
        const int k = k0 + j;
        float v = 0.0f;
        if (n < nact) {
            if (k < khp) {
                if (k < kact) v = W[k * nact + n];
            } else {
                const int xr = k - khp;
                if (xr < 37) v = W[(kact + xr) * nact + n];
            }
        }
        fr.e[j] = f2bf(v);
    }
    *(short8*)(out + (size_t)t * 8) = fr.v;
}

// ---------------------------------------------------------------------------
// One MLP layer with 32x32x16 MFMA. Wave w handles n-tiles {w, w+16, ...}.
// Per K-step (16 k): 1 ds_read_b128 (X-frag, lane: pt=lane&31,
// k=(lane>>5)*8+j) + 1 global_load_dwordx4 (W-frag, L2-resident pack)
// + 1 MFMA (swapped: D[n, pt]).
// D: col pt = lane&31; row n = (reg&3) + 8*(reg>>2) + 4*(lane>>5)
//   -> per lane 4 quads (rq=reg>>2) of 4 consecutive n at
//      nt*32 + rq*8 + (lane>>5)*4  -> 4x ds_write_b64 + float4 bias.
// ---------------------------------------------------------------------------
template<int KHP, int HSEG, int OSEG, int NT, int NACT, int LBASE,
         bool XIN, bool RELU, bool GOUT>
__device__ __forceinline__ void mlayer(const u16* __restrict__ wpack,
                                       const float* __restrict__ bias,
                                       u16* __restrict__ s_act,
                                       float* __restrict__ gout, int p0,
                                       int wave, int lane)
{
    constexpr int KHS = KHP / 16;
    constexpr int KS  = KHS + (XIN ? 4 : 0);
    const int pt = lane & 31;
    const int hl = lane >> 5;
    const u16* wl   = wpack + LBASE + lane * 8;
    const u16* arow = s_act + pt * SROW + hl * 8;

    for (int nt = wave; nt < NT; nt += NWAVES) {
        const u16* bp = wl + (size_t)nt * KS * 512;

        f32x16 acc;
#pragma unroll
        for (int i = 0; i < 16; ++i) acc[i] = 0.f;

#pragma unroll
        for (int s = 0; s < KS; ++s) {
            const int ab = (s < KHS) ? (HSEG + s * 16)
                                     : (XIN_OFF + (s - KHS) * 16);
            const short8 a = *(const short8*)(arow + ab);
            const short8 b = *(const short8*)(bp + (size_t)s * 512);
            acc = __builtin_amdgcn_mfma_f32_32x32x16_bf16(b, a, acc, 0, 0, 0);
        }

        if (GOUT) {
            // n = (reg&3)+8*(reg>>2)+4*hl: n=0,1 -> regs 0,1 at hl=0.
            if (hl == 0) {
                float2 o;
                o.x = acc[0] + bias[0];
                o.y = acc[1] + bias[1];
                *(float2*)(gout + (size_t)(p0 + pt) * 2) = o;
            }
        } else {
#pragma unroll
            for (int rq = 0; rq < 4; ++rq) {
                const int bn = nt * 32 + rq * 8 + hl * 4;
                float bv[4];
                if (bn + 4 <= NACT) {
                    const f32x4 b4 = *(const f32x4*)(bias + bn);
                    bv[0] = b4[0]; bv[1] = b4[1]; bv[2] = b4[2]; bv[3] = b4[3];
                } else {
#pragma unroll
                    for (int e = 0; e < 4; ++e)
                        bv[e] = (bn + e < NACT) ? bias[bn + e] : 0.f;
                }
                short4v o;
#pragma unroll
                for (int e = 0; e < 4; ++e) {
                    float v = acc[rq * 4 + e] + bv[e];
                    if (RELU) v = fmaxf(v, 0.f);
                    o[e] = (short)f2bf(v);
                }
                *(short4v*)(s_act + (size_t)pt * SROW + OSEG + bn) = o;
            }
        }
    }
}

struct MainParams {
    const float* lr;     // [B,2,64,64]
    const float* ctx;    // [B,32,64,64]
    const float* eps;    // [B,64,64]
    const float* coord;  // [B,N,2]
    const float* Bb[7];  // biases (fp32)
    const u16*   wpack;  // packed bf16 weights in d_ws
    float*       out;    // [B,N,2]
};

__global__ __launch_bounds__(NTH, 8)   // 8 waves/EU = 32 waves/CU = 2 blocks
void cont_decoder_mfma(MainParams p)
{
    extern __shared__ u16 s_act[];         // MPTS*SROW bf16 = 55808 B
    __shared__ int   s_x0[MPTS], s_y0[MPTS];
    __shared__ float s_wx[MPTS], s_wy[MPTS];

    const int tid  = threadIdx.x;
    const int wave = tid >> 6;
    const int lane = tid & 63;
    const int p0   = blockIdx.x * MPTS;
    const int b    = p0 >> 14;             // 16384 points per batch

    // ---- zero pad regions: xin[37..64) and hA[528..544) (cols 592..608) ----
    for (int i = tid; i < MPTS * 43; i += NTH) {
        const int pt = i / 43, c = i % 43;
        const int col = (c < 27) ? (37 + c) : (592 + (c - 27));
        s_act[pt * SROW + col] = 0;
    }

    // ---- bilinear params + coord features ----
    if (tid < MPTS) {
        const int pt = p0 + tid;
        const float cx = p.coord[2 * pt];
        const float cy = p.coord[2 * pt + 1];
        const float gx = (cx + 1.0f) * 32.0f - 0.5f;   // align_corners=False
        const float gy = (cy + 1.0f) * 32.0f - 0.5f;
        const float fx0 = floorf(gx), fy0 = floorf(gy);
        s_x0[tid] = (int)fx0;
        s_y0[tid] = (int)fy0;
        s_wx[tid] = gx - fx0;
        s_wy[tid] = gy - fy0;
        s_act[tid * SROW + 32] = f2bf(cx);
        s_act[tid * SROW + 33] = f2bf(cy);
    }
    __syncthreads();

    // ---- sample 35 channels/point (ref swaps spatial axes: val = g[b,c,x,y]) ----
    for (int idx = tid; idx < MPTS * 35; idx += NTH) {
        const int t = idx / 35;
        const int c = idx % 35;
        const float* base;
        int col;
        if (c < 32)      { base = p.ctx + (size_t)(b * 32 + c) * 4096;       col = c; }
        else if (c < 34) { base = p.lr  + (size_t)(b * 2 + (c - 32)) * 4096; col = 34 + (c - 32); }
        else             { base = p.eps + (size_t)b * 4096;                   col = 36; }

        const int   x0 = s_x0[t], y0 = s_y0[t];
        const float wx = s_wx[t], wy = s_wy[t];
        const int x1 = x0 + 1, y1 = y0 + 1;
        const bool xv0 = (x0 >= 0) & (x0 < 64);
        const bool xv1 = (x1 >= 0) & (x1 < 64);
        const bool yv0 = (y0 >= 0) & (y0 < 64);
        const bool yv1 = (y1 >= 0) & (y1 < 64);
        const int xc0 = min(max(x0, 0), 63), xc1 = min(max(x1, 0), 63);
        const int yc0 = min(max(y0, 0), 63), yc1 = min(max(y1, 0), 63);

        const float w00 = (1.0f - wx) * (1.0f - wy) * ((xv0 && yv0) ? 1.0f : 0.0f);
        const float w10 = wx * (1.0f - wy)          * ((xv1 && yv0) ? 1.0f : 0.0f);
        const float w01 = (1.0f - wx) * wy          * ((xv0 && yv1) ? 1.0f : 0.0f);
        const float w11 = wx * wy                   * ((xv1 && yv1) ? 1.0f : 0.0f);

        const float val = w00 * base[xc0 * 64 + yc0]
                        + w10 * base[xc1 * 64 + yc0]
                        + w01 * base[xc0 * 64 + yc1]
                        + w11 * base[xc1 * 64 + yc1];
        s_act[t * SROW + col] = f2bf(val);
    }
    __syncthreads();

    // ---- MLP:  xin(37p64) ->W0-> hA(516p544) ->W1-> hB(256) ->W2-> hA(128)
    //            ->W3-> hB(64) ->W4-> hA(32) ->W5-> hB(16p32) ->W6-> out(2)
    // All layers 32x32x16; KS counts 16-wide k-steps; LBASE = frag64_base*512.
    //       KHP  HSEG    OSEG    NT  NACT LBASE    XIN   RELU   GOUT
    mlayer<  0,  HA_OFF, HA_OFF, 17, 516, 0,       true,  true,  false>(p.wpack, p.Bb[0], s_act, nullptr, p0, wave, lane);
    __syncthreads();
    mlayer<544,  HA_OFF, HB_OFF,  8, 256, 34816,   true,  true,  false>(p.wpack, p.Bb[1], s_act, nullptr, p0, wave, lane);
    __syncthreads();
    mlayer<256,  HB_OFF, HA_OFF,  4, 128, 190464,  true,  true,  false>(p.wpack, p.Bb[2], s_act, nullptr, p0, wave, lane);
    __syncthreads();
    mlayer<128,  HA_OFF, HB_OFF,  2,  64, 231424,  true,  true,  false>(p.wpack, p.Bb[3], s_act, nullptr, p0, wave, lane);
    __syncthreads();
    mlayer< 64,  HB_OFF, HA_OFF,  1,  32, 243712,  true,  true,  false>(p.wpack, p.Bb[4], s_act, nullptr, p0, wave, lane);
    __syncthreads();
    mlayer< 32,  HA_OFF, HB_OFF,  1,  16, 247808,  true,  true,  false>(p.wpack, p.Bb[5], s_act, nullptr, p0, wave, lane);
    __syncthreads();
    mlayer< 32,  HB_OFF, 0,       1,   2, 250880,  false, false, true >(p.wpack, p.Bb[6], s_act, p.out,   p0, wave, lane);
}

extern "C" void kernel_launch(void* const* d_in, const int* in_sizes, int n_in,
                              void* d_out, int out_size, void* d_ws, size_t ws_size,
                              hipStream_t stream)
{
    WPtrs wp;
    for (int l = 0; l < 7; ++l) wp.W[l] = (const float*)d_in[4 + 2 * l];

    MainParams p;
    p.lr    = (const float*)d_in[0];
    p.ctx   = (const float*)d_in[1];
    p.eps   = (const float*)d_in[2];
    p.coord = (const float*)d_in[3];
    for (int l = 0; l < 7; ++l) p.Bb[l] = (const float*)d_in[5 + 2 * l];
    p.wpack = (const u16*)d_ws;
    p.out   = (float*)d_out;

    // Opt in to large dynamic LDS (idempotent; not a stream op, capture-safe).
    hipFuncSetAttribute((const void*)cont_decoder_mfma,
                        hipFuncAttributeMaxDynamicSharedMemorySize, LDSBYTES);

    // 492 frag64 x 64 lanes = 31488 threads = 123 blocks x 256
    hipLaunchKernelGGL(pack_weights, dim3(123), dim3(256), 0, stream, wp, (u16*)d_ws);
    hipLaunchKernelGGL(cont_decoder_mfma, dim3(GRIDX), dim3(NTH), LDSBYTES, stream, p);
}